// Round 2
// baseline (1150.332 us; speedup 1.0000x reference)
//
#include <hip/hip_runtime.h>
#include <hip/hip_bf16.h>

// MoBoAlignerAttention on MI355X — round 1.
// Change vs round 0: gen_T now reproduces JAX's *partitionable* threefry path
// (default since jax 0.5.0): per element i, counter=(0,i), bits = out0^out1.
// Round 0 used the legacy split-in-half counter scheme; everything else is
// unchanged (pipeline was hand-verified; residual 3.3e-2 error is consistent
// with wrong-T only).
//
// Pipeline:
//  1) gemm_scores : scores[n][j][k] = mel[n,j,:]·enc[n,k,:] / sqrt(512)   (fp32 VALU tiled)
//  2) gen_T       : JAX Threefry-2x32 (partitionable) uniform(key(1234),(32,1,384))
//  3) softmax_rows: s_alignment -> d_out  (softmax over k)
//  4) cond_prob_k : sc=exp(scores/T); cp = sc / (window_19(sc)+1e-8), written k-major (cpT[n][k][j])
//  5) phase1_a    : sequential-over-k scan  a_k[j] = sum_{t=j-20..j-2} a_{k-1}[t]*cp_{k-1}[t]
//  6) phase2_B    : B[j,k] = sum_{d=2..19} a[j-d,k] * W_{20-d}(j,k)
//  7) transpose_B : BT[n][k][j] -> d_out[n][1][j][k]
//  8) gemm_att    : att[n][j][m] = sum_k BT[n][k][j]*enc[n][k][m]     (fp32 VALU tiled)

#define NB 32
#define TD 1024
#define TE 384
#define DM 512

// ---------------------------------------------------------------- threefry
__device__ __forceinline__ void tf_round(unsigned &x0, unsigned &x1, int r) {
  x0 += x1;
  x1 = (x1 << r) | (x1 >> (32 - r));
  x1 ^= x0;
}

__device__ __forceinline__ void threefry2x32(unsigned c0, unsigned c1,
                                             unsigned &o0, unsigned &o1) {
  const unsigned k0 = 0u, k1 = 1234u;
  const unsigned k2 = 0u ^ 1234u ^ 0x1BD11BDAu;
  unsigned x0 = c0 + k0, x1 = c1 + k1;
  tf_round(x0, x1, 13); tf_round(x0, x1, 15); tf_round(x0, x1, 26); tf_round(x0, x1, 6);
  x0 += k1; x1 += k2 + 1u;
  tf_round(x0, x1, 17); tf_round(x0, x1, 29); tf_round(x0, x1, 16); tf_round(x0, x1, 24);
  x0 += k2; x1 += k0 + 2u;
  tf_round(x0, x1, 13); tf_round(x0, x1, 15); tf_round(x0, x1, 26); tf_round(x0, x1, 6);
  x0 += k0; x1 += k1 + 3u;
  tf_round(x0, x1, 17); tf_round(x0, x1, 29); tf_round(x0, x1, 16); tf_round(x0, x1, 24);
  x0 += k1; x1 += k2 + 4u;
  tf_round(x0, x1, 13); tf_round(x0, x1, 15); tf_round(x0, x1, 26); tf_round(x0, x1, 6);
  x0 += k2; x1 += k0 + 5u;
  o0 = x0; o1 = x1;
}

__device__ __forceinline__ float tf_uniform(unsigned bits) {
  return __uint_as_float((bits >> 9) | 0x3F800000u) - 1.0f;
}

// Partitionable threefry (jax >= 0.5.0 default): per element i,
// counter = (hi32(i)=0, lo32(i)=i); 32-bit draw = out0 ^ out1.
__global__ __launch_bounds__(256) void gen_T(float *__restrict__ Tbuf) {
  int i = blockIdx.x * blockDim.x + threadIdx.x;  // 0..12287
  if (i >= NB * TE) return;
  unsigned o0, o1;
  threefry2x32(0u, (unsigned)i, o0, o1);
  Tbuf[i] = tf_uniform(o0 ^ o1) + 0.5f;  // T = u*(1.5-0.5)+0.5
}

// ---------------------------------------------------------------- gemm1
__global__ __launch_bounds__(256) void gemm_scores(
    const float *__restrict__ enc, const float *__restrict__ mel,
    float *__restrict__ scores) {
  const int n = blockIdx.z;
  const int k0 = blockIdx.x * 64;
  const int j0 = blockIdx.y * 64;
  const int tid = threadIdx.x;
  const int tx4 = (tid & 15) * 4;
  const int ty4 = (tid >> 4) * 4;
  const int lr = tid >> 2;          // 0..63 tile row
  const int lc = (tid & 3) * 4;     // 0,4,8,12 d offset
  const float *A = mel + (size_t)n * TD * DM;   // [j][d]
  const float *Bm = enc + (size_t)n * TE * DM;  // [k][d]
  __shared__ float As[16][72];
  __shared__ float Bs[16][72];
  float acc[4][4];
#pragma unroll
  for (int i = 0; i < 4; ++i)
#pragma unroll
    for (int c = 0; c < 4; ++c) acc[i][c] = 0.f;

  for (int d0 = 0; d0 < DM; d0 += 16) {
    float4 av = *(const float4 *)(A + (size_t)(j0 + lr) * DM + d0 + lc);
    float4 bv = *(const float4 *)(Bm + (size_t)(k0 + lr) * DM + d0 + lc);
    __syncthreads();
    As[lc + 0][lr] = av.x; As[lc + 1][lr] = av.y; As[lc + 2][lr] = av.z; As[lc + 3][lr] = av.w;
    Bs[lc + 0][lr] = bv.x; Bs[lc + 1][lr] = bv.y; Bs[lc + 2][lr] = bv.z; Bs[lc + 3][lr] = bv.w;
    __syncthreads();
#pragma unroll
    for (int d = 0; d < 16; ++d) {
      const float4 a4 = *(const float4 *)(&As[d][ty4]);
      const float4 b4 = *(const float4 *)(&Bs[d][tx4]);
      const float ar_[4] = {a4.x, a4.y, a4.z, a4.w};
      const float br_[4] = {b4.x, b4.y, b4.z, b4.w};
#pragma unroll
      for (int i = 0; i < 4; ++i)
#pragma unroll
        for (int c = 0; c < 4; ++c)
          acc[i][c] = fmaf(ar_[i], br_[c], acc[i][c]);
    }
  }
  const float scale = 0.0441941738241592f;  // 1/sqrt(512)
#pragma unroll
  for (int i = 0; i < 4; ++i) {
    float4 o = make_float4(acc[i][0] * scale, acc[i][1] * scale,
                           acc[i][2] * scale, acc[i][3] * scale);
    *(float4 *)(scores + ((size_t)n * TD + j0 + ty4 + i) * TE + k0 + tx4) = o;
  }
}

// ---------------------------------------------------------------- softmax
__global__ __launch_bounds__(64) void softmax_rows(
    const float *__restrict__ scores, float *__restrict__ out1) {
  const int row = blockIdx.x;  // n*TD + j
  const int n = row >> 10;
  const int j = row & 1023;
  const int tid = threadIdx.x;
  const float *s = scores + (size_t)row * TE;
  float v[6];
#pragma unroll
  for (int i = 0; i < 6; ++i) v[i] = s[tid + 64 * i];
  float m = v[0];
#pragma unroll
  for (int i = 1; i < 6; ++i) m = fmaxf(m, v[i]);
#pragma unroll
  for (int off = 32; off; off >>= 1) m = fmaxf(m, __shfl_xor(m, off));
  float e[6], sum = 0.f;
#pragma unroll
  for (int i = 0; i < 6; ++i) { e[i] = __expf(v[i] - m); sum += e[i]; }
#pragma unroll
  for (int off = 32; off; off >>= 1) sum += __shfl_xor(sum, off);
  const float r = 1.0f / sum;
  float *dst = out1 + (size_t)n * (2 * TD * TE) + (size_t)j * TE;
#pragma unroll
  for (int i = 0; i < 6; ++i) dst[tid + 64 * i] = e[i] * r;
}

// ---------------------------------------------------------------- cond_prob
__global__ __launch_bounds__(128) void cond_prob_k(
    const float *__restrict__ scores, const float *__restrict__ Tbuf,
    float *__restrict__ cpT) {
  const int n = blockIdx.y;
  const int k0 = blockIdx.x * 128;
  const int tid = threadIdx.x;
  const int k = k0 + tid;
  __shared__ float tile[32][129];  // [jj][kk]
  const float invT = 1.0f / Tbuf[n * TE + k];
  const float *sb = scores + (size_t)n * TD * TE + k;
  float win = 0.f;
  for (int j = TD - 1; j >= 0; --j) {
    const float e = __expf(sb[(size_t)j * TE] * invT);
    if ((j & 63) == 0) {
      // periodic exact refresh to kill running-sum drift
      float s2 = 0.f;
      const int hi = min(j + 18, TD - 1);
      for (int t = j; t <= hi; ++t) s2 += __expf(sb[(size_t)t * TE] * invT);
      win = s2;
    } else {
      win += e;
      if (j + 19 <= TD - 1) win -= __expf(sb[(size_t)(j + 19) * TE] * invT);
    }
    tile[j & 31][tid] = e / (win + 1e-8f);
    if ((j & 31) == 0) {
      __syncthreads();
      const int kk = tid >> 5;   // 0..3
      const int jj = tid & 31;
#pragma unroll
      for (int r = 0; r < 128; r += 4) {
        const int krow = r + kk;
        cpT[((size_t)n * TE + k0 + krow) * TD + j + jj] = tile[jj][krow];
      }
      __syncthreads();
    }
  }
}

// ---------------------------------------------------------------- phase 1 (a scan)
__global__ __launch_bounds__(128) void phase1_a(
    const float *__restrict__ cpT, float *__restrict__ aT) {
  const int n = blockIdx.x;
  const int tid = threadIdx.x;
  const int j0 = tid * 8;
  __shared__ float qbuf[2][24 + TD];
  if (tid < 24) { qbuf[0][tid] = 0.f; qbuf[1][tid] = 0.f; }
  float a[8];
#pragma unroll
  for (int i = 0; i < 8; ++i) a[i] = 0.f;
  if (tid == 0) a[0] = 1.f;  // a0
  const float *cpn = cpT + (size_t)n * TE * TD;
  float *an = aT + (size_t)n * TE * TD;
  // cp registers hold column max(k-1,0) at step k; start with col 0
  float4 c0 = *(const float4 *)(cpn + j0);
  float4 c1 = *(const float4 *)(cpn + j0 + 4);
  __syncthreads();
  for (int k = 0; k < TE; ++k) {
    const float cp[8] = {c0.x, c0.y, c0.z, c0.w, c1.x, c1.y, c1.z, c1.w};
    if (k + 1 < TE) {  // prefetch col k for step k+1
      c0 = *(const float4 *)(cpn + (size_t)k * TD + j0);
      c1 = *(const float4 *)(cpn + (size_t)k * TD + j0 + 4);
    }
    float *q = &qbuf[k & 1][24];
    float4 q0 = make_float4(a[0] * cp[0], a[1] * cp[1], a[2] * cp[2], a[3] * cp[3]);
    float4 q1 = make_float4(a[4] * cp[4], a[5] * cp[5], a[6] * cp[6], a[7] * cp[7]);
    *(float4 *)(q + j0) = q0;
    *(float4 *)(q + j0 + 4) = q1;
    __syncthreads();
    float w[32];  // q[j0-24 .. j0+7]
#pragma unroll
    for (int b = 0; b < 8; ++b) {
      float4 t = *(const float4 *)(q + j0 - 24 + b * 4);
      w[b * 4 + 0] = t.x; w[b * 4 + 1] = t.y; w[b * 4 + 2] = t.z; w[b * 4 + 3] = t.w;
    }
    // a_new[j] = sum_{t=j-20}^{j-2} q[t]
    float s = 0.f;
#pragma unroll
    for (int t = 4; t <= 22; ++t) s += w[t];
    a[0] = s;
#pragma unroll
    for (int i = 1; i < 8; ++i) { s += w[22 + i] - w[3 + i]; a[i] = s; }
    *(float4 *)(an + (size_t)k * TD + j0) = make_float4(a[0], a[1], a[2], a[3]);
    *(float4 *)(an + (size_t)k * TD + j0 + 4) = make_float4(a[4], a[5], a[6], a[7]);
  }
}

// ---------------------------------------------------------------- phase 2 (B)
__global__ __launch_bounds__(256) void phase2_B(
    const float *__restrict__ cpT, const float *__restrict__ aT,
    float *__restrict__ BT) {
  const int k = blockIdx.x;
  const int n = blockIdx.y;
  const int tid = threadIdx.x;
  const float *cpc = cpT + ((size_t)n * TE + k) * TD;
  const float *ac = aT + ((size_t)n * TE + k) * TD;
  __shared__ float a_l[20 + TD];       // a_l[20+j] = a[j]; 20 zeros below
  __shared__ float cp_l[TD + 24];      // cp_l[j]; index >=1023 forced to 0 (clamp rule)
  float4 av = *(const float4 *)(ac + tid * 4);
  *(float4 *)(&a_l[20 + tid * 4]) = av;
  float4 cv = *(const float4 *)(cpc + tid * 4);
  if (tid == 255) cv.w = 0.f;          // cp[1023] never contributes to W windows
  *(float4 *)(&cp_l[tid * 4]) = cv;
  if (tid < 20) a_l[tid] = 0.f;
  if (tid < 24) cp_l[TD + tid] = 0.f;
  __syncthreads();
  const int j0 = tid * 4;
  float ar[21], cpr[21];
#pragma unroll
  for (int t = 0; t < 21; ++t) ar[t] = a_l[20 + j0 - 19 + t];  // a[j0-19+t]
#pragma unroll
  for (int t = 0; t < 21; ++t) cpr[t] = cp_l[j0 + t];          // cp[j0+t]
  float Bo[4];
#pragma unroll
  for (int i = 0; i < 4; ++i) {
    float W = 0.f, acc2 = 0.f;
#pragma unroll
    for (int d = 19; d >= 2; --d) {
      W += cpr[i + 19 - d];             // += cp[j+19-d]  (w = 20-d running window)
      acc2 = fmaf(ar[19 + i - d], W, acc2);  // += a[j-d]*W
    }
    Bo[i] = acc2;
  }
  *(float4 *)(BT + ((size_t)n * TE + k) * TD + j0) =
      make_float4(Bo[0], Bo[1], Bo[2], Bo[3]);
}

// ---------------------------------------------------------------- transpose
__global__ __launch_bounds__(256) void transpose_B(
    const float *__restrict__ BT, float *__restrict__ out1) {
  __shared__ float tile[32][33];
  const int n = blockIdx.z;
  const int k0 = blockIdx.x * 32;
  const int j0 = blockIdx.y * 32;
  const int tx = threadIdx.x & 31;
  const int ty = threadIdx.x >> 5;  // 0..7
  const float *src = BT + (size_t)n * TE * TD;
#pragma unroll
  for (int r = 0; r < 4; ++r) {
    const int kk = ty + r * 8;
    tile[kk][tx] = src[(size_t)(k0 + kk) * TD + j0 + tx];
  }
  __syncthreads();
  float *dst = out1 + (size_t)n * (2 * TD * TE) + (size_t)TD * TE;
#pragma unroll
  for (int r = 0; r < 4; ++r) {
    const int jj = ty + r * 8;
    dst[(size_t)(j0 + jj) * TE + k0 + tx] = tile[tx][jj];
  }
}

// ---------------------------------------------------------------- gemm2
__global__ __launch_bounds__(256) void gemm_att(
    const float *__restrict__ BT, const float *__restrict__ enc,
    float *__restrict__ out0) {
  const int n = blockIdx.z;
  const int m0 = blockIdx.x * 64;
  const int j0 = blockIdx.y * 64;
  const int tid = threadIdx.x;
  const int tx4 = (tid & 15) * 4;
  const int ty4 = (tid >> 4) * 4;
  const int lk = tid >> 4;          // 0..15 k row
  const int lo = (tid & 15) * 4;    // 0..60 col offset
  const float *Ab = BT + (size_t)n * TE * TD;   // [k][j]
  const float *Bb = enc + (size_t)n * TE * DM;  // [k][m]
  __shared__ float As[16][72];
  __shared__ float Bs[16][72];
  float acc[4][4];
#pragma unroll
  for (int i = 0; i < 4; ++i)
#pragma unroll
    for (int c = 0; c < 4; ++c) acc[i][c] = 0.f;

  for (int kb = 0; kb < TE; kb += 16) {
    float4 av = *(const float4 *)(Ab + (size_t)(kb + lk) * TD + j0 + lo);
    float4 bv = *(const float4 *)(Bb + (size_t)(kb + lk) * DM + m0 + lo);
    __syncthreads();
    *(float4 *)(&As[lk][lo]) = av;
    *(float4 *)(&Bs[lk][lo]) = bv;
    __syncthreads();
#pragma unroll
    for (int d = 0; d < 16; ++d) {
      const float4 a4 = *(const float4 *)(&As[d][ty4]);
      const float4 b4 = *(const float4 *)(&Bs[d][tx4]);
      const float ar_[4] = {a4.x, a4.y, a4.z, a4.w};
      const float br_[4] = {b4.x, b4.y, b4.z, b4.w};
#pragma unroll
      for (int i = 0; i < 4; ++i)
#pragma unroll
        for (int c = 0; c < 4; ++c)
          acc[i][c] = fmaf(ar_[i], br_[c], acc[i][c]);
    }
  }
#pragma unroll
  for (int i = 0; i < 4; ++i) {
    float4 o = make_float4(acc[i][0], acc[i][1], acc[i][2], acc[i][3]);
    *(float4 *)(out0 + ((size_t)n * TD + j0 + ty4 + i) * DM + m0 + tx4) = o;
  }
}

// ---------------------------------------------------------------- launch
extern "C" void kernel_launch(void *const *d_in, const int *in_sizes, int n_in,
                              void *d_out, int out_size, void *d_ws,
                              size_t ws_size, hipStream_t stream) {
  (void)in_sizes; (void)n_in; (void)out_size; (void)ws_size;
  const float *enc = (const float *)d_in[0];  // [32][384][512]
  const float *mel = (const float *)d_in[1];  // [32][1024][512]
  float *out = (float *)d_out;
  float *out0 = out;                              // att_out [32][1024][512]
  float *out1 = out + (size_t)NB * TD * DM;       // stacked [32][2][1024][384]

  const size_t SZ = (size_t)NB * TD * TE;  // 12,582,912 floats
  float *ws = (float *)d_ws;
  float *ws_scores = ws;            // scores [n][j][k]
  float *ws_cpT = ws + SZ;          // cond_prob [n][k][j]
  float *ws_aT = ws + 2 * SZ;       // a [n][k][j]
  float *ws_T = ws + 3 * SZ;        // T [n][k] (12288)
  float *ws_BT = ws_scores;         // B [n][k][j] — reuses scores region

  gemm_scores<<<dim3(TE / 64, TD / 64, NB), 256, 0, stream>>>(enc, mel, ws_scores);
  gen_T<<<48, 256, 0, stream>>>(ws_T);
  softmax_rows<<<NB * TD, 64, 0, stream>>>(ws_scores, out1);
  cond_prob_k<<<dim3(TE / 128, NB), 128, 0, stream>>>(ws_scores, ws_T, ws_cpT);
  phase1_a<<<NB, 128, 0, stream>>>(ws_cpT, ws_aT);
  phase2_B<<<dim3(TE, NB), 256, 0, stream>>>(ws_cpT, ws_aT, ws_BT);
  transpose_B<<<dim3(TE / 32, TD / 32, NB), 256, 0, stream>>>(ws_BT, out1);
  gemm_att<<<dim3(DM / 64, TD / 64, NB), 256, 0, stream>>>(ws_BT, enc, out0);
}

// Round 3
// 733.472 us; speedup vs baseline: 1.5683x; 1.5683x over previous
//
#include <hip/hip_runtime.h>
#include <hip/hip_bf16.h>

// MoBoAlignerAttention on MI355X — round 2.
// Change vs round 1: cond_prob_k (444 µs, 2% occupancy, 2% VALU — latency-bound
// sequential j-loop) replaced by cond_prob2: fully parallel j×k tiling with an
// 18-row halo (the 19-wide window is local, not a recurrence). 3072 blocks.
// Everything else unchanged.
//
// Pipeline:
//  1) gemm_scores : scores[n][j][k] = mel[n,j,:]·enc[n,k,:] / sqrt(512)   (fp32 VALU tiled)
//  2) gen_T       : JAX Threefry-2x32 (partitionable) uniform(key(1234),(32,1,384))
//  3) softmax_rows: s_alignment -> d_out  (softmax over k)
//  4) cond_prob2  : sc=exp(scores/T); cp = sc / (window_19(sc)+1e-8), written k-major (cpT[n][k][j])
//  5) phase1_a    : sequential-over-k scan  a_k[j] = sum_{t=j-20..j-2} a_{k-1}[t]*cp_{k-1}[t]
//  6) phase2_B    : B[j,k] = sum_{d=2..19} a[j-d,k] * W_{20-d}(j,k)
//  7) transpose_B : BT[n][k][j] -> d_out[n][1][j][k]
//  8) gemm_att    : att[n][j][m] = sum_k BT[n][k][j]*enc[n][k][m]     (fp32 VALU tiled)

#define NB 32
#define TD 1024
#define TE 384
#define DM 512

// ---------------------------------------------------------------- threefry
__device__ __forceinline__ void tf_round(unsigned &x0, unsigned &x1, int r) {
  x0 += x1;
  x1 = (x1 << r) | (x1 >> (32 - r));
  x1 ^= x0;
}

__device__ __forceinline__ void threefry2x32(unsigned c0, unsigned c1,
                                             unsigned &o0, unsigned &o1) {
  const unsigned k0 = 0u, k1 = 1234u;
  const unsigned k2 = 0u ^ 1234u ^ 0x1BD11BDAu;
  unsigned x0 = c0 + k0, x1 = c1 + k1;
  tf_round(x0, x1, 13); tf_round(x0, x1, 15); tf_round(x0, x1, 26); tf_round(x0, x1, 6);
  x0 += k1; x1 += k2 + 1u;
  tf_round(x0, x1, 17); tf_round(x0, x1, 29); tf_round(x0, x1, 16); tf_round(x0, x1, 24);
  x0 += k2; x1 += k0 + 2u;
  tf_round(x0, x1, 13); tf_round(x0, x1, 15); tf_round(x0, x1, 26); tf_round(x0, x1, 6);
  x0 += k0; x1 += k1 + 3u;
  tf_round(x0, x1, 17); tf_round(x0, x1, 29); tf_round(x0, x1, 16); tf_round(x0, x1, 24);
  x0 += k1; x1 += k2 + 4u;
  tf_round(x0, x1, 13); tf_round(x0, x1, 15); tf_round(x0, x1, 26); tf_round(x0, x1, 6);
  x0 += k2; x1 += k0 + 5u;
  o0 = x0; o1 = x1;
}

__device__ __forceinline__ float tf_uniform(unsigned bits) {
  return __uint_as_float((bits >> 9) | 0x3F800000u) - 1.0f;
}

// Partitionable threefry (jax >= 0.5.0 default): per element i,
// counter = (hi32(i)=0, lo32(i)=i); 32-bit draw = out0 ^ out1.
__global__ __launch_bounds__(256) void gen_T(float *__restrict__ Tbuf) {
  int i = blockIdx.x * blockDim.x + threadIdx.x;  // 0..12287
  if (i >= NB * TE) return;
  unsigned o0, o1;
  threefry2x32(0u, (unsigned)i, o0, o1);
  Tbuf[i] = tf_uniform(o0 ^ o1) + 0.5f;  // T = u*(1.5-0.5)+0.5
}

// ---------------------------------------------------------------- gemm1
__global__ __launch_bounds__(256) void gemm_scores(
    const float *__restrict__ enc, const float *__restrict__ mel,
    float *__restrict__ scores) {
  const int n = blockIdx.z;
  const int k0 = blockIdx.x * 64;
  const int j0 = blockIdx.y * 64;
  const int tid = threadIdx.x;
  const int tx4 = (tid & 15) * 4;
  const int ty4 = (tid >> 4) * 4;
  const int lr = tid >> 2;          // 0..63 tile row
  const int lc = (tid & 3) * 4;     // 0,4,8,12 d offset
  const float *A = mel + (size_t)n * TD * DM;   // [j][d]
  const float *Bm = enc + (size_t)n * TE * DM;  // [k][d]
  __shared__ float As[16][72];
  __shared__ float Bs[16][72];
  float acc[4][4];
#pragma unroll
  for (int i = 0; i < 4; ++i)
#pragma unroll
    for (int c = 0; c < 4; ++c) acc[i][c] = 0.f;

  for (int d0 = 0; d0 < DM; d0 += 16) {
    float4 av = *(const float4 *)(A + (size_t)(j0 + lr) * DM + d0 + lc);
    float4 bv = *(const float4 *)(Bm + (size_t)(k0 + lr) * DM + d0 + lc);
    __syncthreads();
    As[lc + 0][lr] = av.x; As[lc + 1][lr] = av.y; As[lc + 2][lr] = av.z; As[lc + 3][lr] = av.w;
    Bs[lc + 0][lr] = bv.x; Bs[lc + 1][lr] = bv.y; Bs[lc + 2][lr] = bv.z; Bs[lc + 3][lr] = bv.w;
    __syncthreads();
#pragma unroll
    for (int d = 0; d < 16; ++d) {
      const float4 a4 = *(const float4 *)(&As[d][ty4]);
      const float4 b4 = *(const float4 *)(&Bs[d][tx4]);
      const float ar_[4] = {a4.x, a4.y, a4.z, a4.w};
      const float br_[4] = {b4.x, b4.y, b4.z, b4.w};
#pragma unroll
      for (int i = 0; i < 4; ++i)
#pragma unroll
        for (int c = 0; c < 4; ++c)
          acc[i][c] = fmaf(ar_[i], br_[c], acc[i][c]);
    }
  }
  const float scale = 0.0441941738241592f;  // 1/sqrt(512)
#pragma unroll
  for (int i = 0; i < 4; ++i) {
    float4 o = make_float4(acc[i][0] * scale, acc[i][1] * scale,
                           acc[i][2] * scale, acc[i][3] * scale);
    *(float4 *)(scores + ((size_t)n * TD + j0 + ty4 + i) * TE + k0 + tx4) = o;
  }
}

// ---------------------------------------------------------------- softmax
__global__ __launch_bounds__(64) void softmax_rows(
    const float *__restrict__ scores, float *__restrict__ out1) {
  const int row = blockIdx.x;  // n*TD + j
  const int n = row >> 10;
  const int j = row & 1023;
  const int tid = threadIdx.x;
  const float *s = scores + (size_t)row * TE;
  float v[6];
#pragma unroll
  for (int i = 0; i < 6; ++i) v[i] = s[tid + 64 * i];
  float m = v[0];
#pragma unroll
  for (int i = 1; i < 6; ++i) m = fmaxf(m, v[i]);
#pragma unroll
  for (int off = 32; off; off >>= 1) m = fmaxf(m, __shfl_xor(m, off));
  float e[6], sum = 0.f;
#pragma unroll
  for (int i = 0; i < 6; ++i) { e[i] = __expf(v[i] - m); sum += e[i]; }
#pragma unroll
  for (int off = 32; off; off >>= 1) sum += __shfl_xor(sum, off);
  const float r = 1.0f / sum;
  float *dst = out1 + (size_t)n * (2 * TD * TE) + (size_t)j * TE;
#pragma unroll
  for (int i = 0; i < 6; ++i) dst[tid + 64 * i] = e[i] * r;
}

// ---------------------------------------------------------------- cond_prob (parallel)
// Window sum over j is 19 wide and *local*: tile j with an 18-row halo.
// Block: 64 k  x 64 j (+18 halo). Threads 256:
//   load phase : 16 lanes/row x float4, rows strided by 16 (6 passes)
//   compute    : thread = (jseg = tid>>6, k = tid&63); 16 j's per thread,
//                19-term seed + 15 slide steps; direct float4 stores to cpT.
__global__ __launch_bounds__(256) void cond_prob2(
    const float *__restrict__ scores, const float *__restrict__ Tbuf,
    float *__restrict__ cpT) {
  const int n = blockIdx.z;
  const int j0 = blockIdx.y * 64;
  const int k0 = blockIdx.x * 64;
  const int tid = threadIdx.x;
  __shared__ float eL[82][65];  // [j_local][k_local], stride 65 -> col walk conflict-free

  {
    const int c4 = (tid & 15) * 4;
    const int r0 = tid >> 4;  // 0..15
    float4 tv = *(const float4 *)(Tbuf + n * TE + k0 + c4);
    const float it0 = 1.0f / tv.x, it1 = 1.0f / tv.y, it2 = 1.0f / tv.z,
                it3 = 1.0f / tv.w;
#pragma unroll
    for (int p = 0; p < 6; ++p) {
      const int r = r0 + p * 16;
      if (r < 82) {
        const int j = j0 + r;
        float4 s;
        if (j < TD) {
          s = *(const float4 *)(scores + ((size_t)n * TD + j) * TE + k0 + c4);
          s.x = __expf(s.x * it0); s.y = __expf(s.y * it1);
          s.z = __expf(s.z * it2); s.w = __expf(s.w * it3);
        } else {
          s = make_float4(0.f, 0.f, 0.f, 0.f);  // e=0 past Tdec (window clamp)
        }
        eL[r][c4 + 0] = s.x; eL[r][c4 + 1] = s.y;
        eL[r][c4 + 2] = s.z; eL[r][c4 + 3] = s.w;
      }
    }
  }
  __syncthreads();

  const int k = tid & 63;
  const int jl0 = (tid >> 6) * 16;  // one wave per jseg
  float e_r[35];                    // eL[jl0 .. jl0+34][k]
#pragma unroll
  for (int t = 0; t < 35; ++t) e_r[t] = eL[jl0 + t][k];
  // seed window for j_local = jl0+15: sum t = 15..33
  float win = 0.f;
#pragma unroll
  for (int t = 15; t <= 33; ++t) win += e_r[t];
  float cp[16];
#pragma unroll
  for (int jl = 15; jl >= 0; --jl) {
    cp[jl] = e_r[jl] / (win + 1e-8f);
    if (jl > 0) win += e_r[jl - 1] - e_r[jl + 18];
  }
  float *dst = cpT + ((size_t)n * TE + k0 + k) * TD + j0 + jl0;
#pragma unroll
  for (int q = 0; q < 4; ++q)
    *(float4 *)(dst + q * 4) =
        make_float4(cp[q * 4], cp[q * 4 + 1], cp[q * 4 + 2], cp[q * 4 + 3]);
}

// ---------------------------------------------------------------- phase 1 (a scan)
__global__ __launch_bounds__(128) void phase1_a(
    const float *__restrict__ cpT, float *__restrict__ aT) {
  const int n = blockIdx.x;
  const int tid = threadIdx.x;
  const int j0 = tid * 8;
  __shared__ float qbuf[2][24 + TD];
  if (tid < 24) { qbuf[0][tid] = 0.f; qbuf[1][tid] = 0.f; }
  float a[8];
#pragma unroll
  for (int i = 0; i < 8; ++i) a[i] = 0.f;
  if (tid == 0) a[0] = 1.f;  // a0
  const float *cpn = cpT + (size_t)n * TE * TD;
  float *an = aT + (size_t)n * TE * TD;
  // cp registers hold column max(k-1,0) at step k; start with col 0
  float4 c0 = *(const float4 *)(cpn + j0);
  float4 c1 = *(const float4 *)(cpn + j0 + 4);
  __syncthreads();
  for (int k = 0; k < TE; ++k) {
    const float cp[8] = {c0.x, c0.y, c0.z, c0.w, c1.x, c1.y, c1.z, c1.w};
    if (k + 1 < TE) {  // prefetch col k for step k+1
      c0 = *(const float4 *)(cpn + (size_t)k * TD + j0);
      c1 = *(const float4 *)(cpn + (size_t)k * TD + j0 + 4);
    }
    float *q = &qbuf[k & 1][24];
    float4 q0 = make_float4(a[0] * cp[0], a[1] * cp[1], a[2] * cp[2], a[3] * cp[3]);
    float4 q1 = make_float4(a[4] * cp[4], a[5] * cp[5], a[6] * cp[6], a[7] * cp[7]);
    *(float4 *)(q + j0) = q0;
    *(float4 *)(q + j0 + 4) = q1;
    __syncthreads();
    float w[32];  // q[j0-24 .. j0+7]
#pragma unroll
    for (int b = 0; b < 8; ++b) {
      float4 t = *(const float4 *)(q + j0 - 24 + b * 4);
      w[b * 4 + 0] = t.x; w[b * 4 + 1] = t.y; w[b * 4 + 2] = t.z; w[b * 4 + 3] = t.w;
    }
    // a_new[j] = sum_{t=j-20}^{j-2} q[t]
    float s = 0.f;
#pragma unroll
    for (int t = 4; t <= 22; ++t) s += w[t];
    a[0] = s;
#pragma unroll
    for (int i = 1; i < 8; ++i) { s += w[22 + i] - w[3 + i]; a[i] = s; }
    *(float4 *)(an + (size_t)k * TD + j0) = make_float4(a[0], a[1], a[2], a[3]);
    *(float4 *)(an + (size_t)k * TD + j0 + 4) = make_float4(a[4], a[5], a[6], a[7]);
  }
}

// ---------------------------------------------------------------- phase 2 (B)
__global__ __launch_bounds__(256) void phase2_B(
    const float *__restrict__ cpT, const float *__restrict__ aT,
    float *__restrict__ BT) {
  const int k = blockIdx.x;
  const int n = blockIdx.y;
  const int tid = threadIdx.x;
  const float *cpc = cpT + ((size_t)n * TE + k) * TD;
  const float *ac = aT + ((size_t)n * TE + k) * TD;
  __shared__ float a_l[20 + TD];       // a_l[20+j] = a[j]; 20 zeros below
  __shared__ float cp_l[TD + 24];      // cp_l[j]; index >=1023 forced to 0 (clamp rule)
  float4 av = *(const float4 *)(ac + tid * 4);
  *(float4 *)(&a_l[20 + tid * 4]) = av;
  float4 cv = *(const float4 *)(cpc + tid * 4);
  if (tid == 255) cv.w = 0.f;          // cp[1023] never contributes to W windows
  *(float4 *)(&cp_l[tid * 4]) = cv;
  if (tid < 20) a_l[tid] = 0.f;
  if (tid < 24) cp_l[TD + tid] = 0.f;
  __syncthreads();
  const int j0 = tid * 4;
  float ar[21], cpr[21];
#pragma unroll
  for (int t = 0; t < 21; ++t) ar[t] = a_l[20 + j0 - 19 + t];  // a[j0-19+t]
#pragma unroll
  for (int t = 0; t < 21; ++t) cpr[t] = cp_l[j0 + t];          // cp[j0+t]
  float Bo[4];
#pragma unroll
  for (int i = 0; i < 4; ++i) {
    float W = 0.f, acc2 = 0.f;
#pragma unroll
    for (int d = 19; d >= 2; --d) {
      W += cpr[i + 19 - d];             // += cp[j+19-d]  (w = 20-d running window)
      acc2 = fmaf(ar[19 + i - d], W, acc2);  // += a[j-d]*W
    }
    Bo[i] = acc2;
  }
  *(float4 *)(BT + ((size_t)n * TE + k) * TD + j0) =
      make_float4(Bo[0], Bo[1], Bo[2], Bo[3]);
}

// ---------------------------------------------------------------- transpose
__global__ __launch_bounds__(256) void transpose_B(
    const float *__restrict__ BT, float *__restrict__ out1) {
  __shared__ float tile[32][33];
  const int n = blockIdx.z;
  const int k0 = blockIdx.x * 32;
  const int j0 = blockIdx.y * 32;
  const int tx = threadIdx.x & 31;
  const int ty = threadIdx.x >> 5;  // 0..7
  const float *src = BT + (size_t)n * TE * TD;
#pragma unroll
  for (int r = 0; r < 4; ++r) {
    const int kk = ty + r * 8;
    tile[kk][tx] = src[(size_t)(k0 + kk) * TD + j0 + tx];
  }
  __syncthreads();
  float *dst = out1 + (size_t)n * (2 * TD * TE) + (size_t)TD * TE;
#pragma unroll
  for (int r = 0; r < 4; ++r) {
    const int jj = ty + r * 8;
    dst[(size_t)(j0 + jj) * TE + k0 + tx] = tile[tx][jj];
  }
}

// ---------------------------------------------------------------- gemm2
__global__ __launch_bounds__(256) void gemm_att(
    const float *__restrict__ BT, const float *__restrict__ enc,
    float *__restrict__ out0) {
  const int n = blockIdx.z;
  const int m0 = blockIdx.x * 64;
  const int j0 = blockIdx.y * 64;
  const int tid = threadIdx.x;
  const int tx4 = (tid & 15) * 4;
  const int ty4 = (tid >> 4) * 4;
  const int lk = tid >> 4;          // 0..15 k row
  const int lo = (tid & 15) * 4;    // 0..60 col offset
  const float *Ab = BT + (size_t)n * TE * TD;   // [k][j]
  const float *Bb = enc + (size_t)n * TE * DM;  // [k][m]
  __shared__ float As[16][72];
  __shared__ float Bs[16][72];
  float acc[4][4];
#pragma unroll
  for (int i = 0; i < 4; ++i)
#pragma unroll
    for (int c = 0; c < 4; ++c) acc[i][c] = 0.f;

  for (int kb = 0; kb < TE; kb += 16) {
    float4 av = *(const float4 *)(Ab + (size_t)(kb + lk) * TD + j0 + lo);
    float4 bv = *(const float4 *)(Bb + (size_t)(kb + lk) * DM + m0 + lo);
    __syncthreads();
    *(float4 *)(&As[lk][lo]) = av;
    *(float4 *)(&Bs[lk][lo]) = bv;
    __syncthreads();
#pragma unroll
    for (int d = 0; d < 16; ++d) {
      const float4 a4 = *(const float4 *)(&As[d][ty4]);
      const float4 b4 = *(const float4 *)(&Bs[d][tx4]);
      const float ar_[4] = {a4.x, a4.y, a4.z, a4.w};
      const float br_[4] = {b4.x, b4.y, b4.z, b4.w};
#pragma unroll
      for (int i = 0; i < 4; ++i)
#pragma unroll
        for (int c = 0; c < 4; ++c)
          acc[i][c] = fmaf(ar_[i], br_[c], acc[i][c]);
    }
  }
#pragma unroll
  for (int i = 0; i < 4; ++i) {
    float4 o = make_float4(acc[i][0], acc[i][1], acc[i][2], acc[i][3]);
    *(float4 *)(out0 + ((size_t)n * TD + j0 + ty4 + i) * DM + m0 + tx4) = o;
  }
}

// ---------------------------------------------------------------- launch
extern "C" void kernel_launch(void *const *d_in, const int *in_sizes, int n_in,
                              void *d_out, int out_size, void *d_ws,
                              size_t ws_size, hipStream_t stream) {
  (void)in_sizes; (void)n_in; (void)out_size; (void)ws_size;
  const float *enc = (const float *)d_in[0];  // [32][384][512]
  const float *mel = (const float *)d_in[1];  // [32][1024][512]
  float *out = (float *)d_out;
  float *out0 = out;                              // att_out [32][1024][512]
  float *out1 = out + (size_t)NB * TD * DM;       // stacked [32][2][1024][384]

  const size_t SZ = (size_t)NB * TD * TE;  // 12,582,912 floats
  float *ws = (float *)d_ws;
  float *ws_scores = ws;            // scores [n][j][k]
  float *ws_cpT = ws + SZ;          // cond_prob [n][k][j]
  float *ws_aT = ws + 2 * SZ;       // a [n][k][j]
  float *ws_T = ws + 3 * SZ;        // T [n][k] (12288)
  float *ws_BT = ws_scores;         // B [n][k][j] — reuses scores region

  gemm_scores<<<dim3(TE / 64, TD / 64, NB), 256, 0, stream>>>(enc, mel, ws_scores);
  gen_T<<<48, 256, 0, stream>>>(ws_T);
  softmax_rows<<<NB * TD, 64, 0, stream>>>(ws_scores, out1);
  cond_prob2<<<dim3(TE / 64, TD / 64, NB), 256, 0, stream>>>(ws_scores, ws_T, ws_cpT);
  phase1_a<<<NB, 128, 0, stream>>>(ws_cpT, ws_aT);
  phase2_B<<<dim3(TE, NB), 256, 0, stream>>>(ws_cpT, ws_aT, ws_BT);
  transpose_B<<<dim3(TE / 32, TD / 32, NB), 256, 0, stream>>>(ws_BT, out1);
  gemm_att<<<dim3(DM / 64, TD / 64, NB), 256, 0, stream>>>(ws_BT, enc, out0);
}

// Round 4
// 541.114 us; speedup vs baseline: 2.1259x; 1.3555x over previous
//
#include <hip/hip_runtime.h>
#include <hip/hip_bf16.h>

// MoBoAlignerAttention on MI355X — round 3.
// Change vs round 2: both fp32 VALU GEMMs (194 + ~170 µs, 66 TF = 42% of the
// fp32 vector ceiling, MfmaUtil=0) replaced by a bf16 MFMA GEMM
// (mfma_f32_16x16x32_bf16, 128x128 tile, 4 waves x 4x4 acc, BK=32).
// Operands pre-converted once: melh/ench staged in the (dead-until-cond_prob2)
// cpT region, encT appended after T (+12.6 MB), Bh (bf16 B) written by
// transpose_B into the dead aT region. Everything else unchanged.
//
// Pipeline:
//  conv_bf16   : mel f32 -> melh bf16 [n][j][d]
//  conv_encT   : enc f32 -> ench bf16 [n][k][d]  +  encT bf16 [n][d][k]
//  gemm_mfma   : scores = melh @ ench^T / sqrt(512)         (bf16 MFMA)
//  gen_T       : JAX Threefry-2x32 (partitionable) uniform
//  softmax_rows: s_alignment -> d_out
//  cond_prob2  : cp = e / (window_19(e)+1e-8), k-major cpT
//  phase1_a    : a_k[j] = sum_{t=j-20..j-2} a_{k-1}[t]*cp_{k-1}[t]
//  phase2_B    : B[j,k] = sum_{d=2..19} a[j-d,k]*W_{20-d}(j,k)
//  transpose_B : BT -> d_out B slot (f32) + Bh bf16 [n][j][k]
//  gemm_mfma   : att = Bh @ encT^T                          (bf16 MFMA)

#define NB 32
#define TD 1024
#define TE 384
#define DM 512

typedef __attribute__((ext_vector_type(8))) short bf16x8;
typedef __attribute__((ext_vector_type(4))) float f32x4;

// f32 -> bf16 round-to-nearest-even
__device__ __forceinline__ ushort f2bf(float f) {
  unsigned u = __float_as_uint(f);
  return (ushort)((u + 0x7FFFu + ((u >> 16) & 1u)) >> 16);
}

// ---------------------------------------------------------------- threefry
__device__ __forceinline__ void tf_round(unsigned &x0, unsigned &x1, int r) {
  x0 += x1;
  x1 = (x1 << r) | (x1 >> (32 - r));
  x1 ^= x0;
}

__device__ __forceinline__ void threefry2x32(unsigned c0, unsigned c1,
                                             unsigned &o0, unsigned &o1) {
  const unsigned k0 = 0u, k1 = 1234u;
  const unsigned k2 = 0u ^ 1234u ^ 0x1BD11BDAu;
  unsigned x0 = c0 + k0, x1 = c1 + k1;
  tf_round(x0, x1, 13); tf_round(x0, x1, 15); tf_round(x0, x1, 26); tf_round(x0, x1, 6);
  x0 += k1; x1 += k2 + 1u;
  tf_round(x0, x1, 17); tf_round(x0, x1, 29); tf_round(x0, x1, 16); tf_round(x0, x1, 24);
  x0 += k2; x1 += k0 + 2u;
  tf_round(x0, x1, 13); tf_round(x0, x1, 15); tf_round(x0, x1, 26); tf_round(x0, x1, 6);
  x0 += k0; x1 += k1 + 3u;
  tf_round(x0, x1, 17); tf_round(x0, x1, 29); tf_round(x0, x1, 16); tf_round(x0, x1, 24);
  x0 += k1; x1 += k2 + 4u;
  tf_round(x0, x1, 13); tf_round(x0, x1, 15); tf_round(x0, x1, 26); tf_round(x0, x1, 6);
  x0 += k2; x1 += k0 + 5u;
  o0 = x0; o1 = x1;
}

__device__ __forceinline__ float tf_uniform(unsigned bits) {
  return __uint_as_float((bits >> 9) | 0x3F800000u) - 1.0f;
}

__global__ __launch_bounds__(256) void gen_T(float *__restrict__ Tbuf) {
  int i = blockIdx.x * blockDim.x + threadIdx.x;  // 0..12287
  if (i >= NB * TE) return;
  unsigned o0, o1;
  threefry2x32(0u, (unsigned)i, o0, o1);
  Tbuf[i] = tf_uniform(o0 ^ o1) + 0.5f;  // T = u*(1.5-0.5)+0.5
}

// ---------------------------------------------------------------- f32 -> bf16 (8 elems/thread)
__global__ __launch_bounds__(256) void conv_bf16(const float *__restrict__ src,
                                                 ushort *__restrict__ dst) {
  const size_t i = ((size_t)blockIdx.x * 256 + threadIdx.x) * 8;
  float4 a = *(const float4 *)(src + i);
  float4 b = *(const float4 *)(src + i + 4);
  uint4 o;
  o.x = (unsigned)f2bf(a.x) | ((unsigned)f2bf(a.y) << 16);
  o.y = (unsigned)f2bf(a.z) | ((unsigned)f2bf(a.w) << 16);
  o.z = (unsigned)f2bf(b.x) | ((unsigned)f2bf(b.y) << 16);
  o.w = (unsigned)f2bf(b.z) | ((unsigned)f2bf(b.w) << 16);
  *(uint4 *)(dst + i) = o;
}

// ---------------------------------------------------------------- enc -> ench + encT
__global__ __launch_bounds__(256) void conv_encT(const float *__restrict__ enc,
                                                 ushort *__restrict__ ench,
                                                 ushort *__restrict__ encT) {
  const int n = blockIdx.z;
  const int d0 = blockIdx.x * 32;
  const int k0 = blockIdx.y * 32;
  __shared__ ushort t[32][33];
  const int row = threadIdx.x >> 3;      // k within tile
  const int c4 = (threadIdx.x & 7) * 4;  // d within tile
  float4 v = *(const float4 *)(enc + ((size_t)n * TE + k0 + row) * DM + d0 + c4);
  ushort4 e;
  e.x = f2bf(v.x); e.y = f2bf(v.y); e.z = f2bf(v.z); e.w = f2bf(v.w);
  t[row][c4 + 0] = e.x; t[row][c4 + 1] = e.y;
  t[row][c4 + 2] = e.z; t[row][c4 + 3] = e.w;
  *(ushort4 *)(ench + ((size_t)n * TE + k0 + row) * DM + d0 + c4) = e;
  __syncthreads();
  const int dr = threadIdx.x >> 3;       // d within tile
  const int kc = (threadIdx.x & 7) * 4;  // k within tile
  ushort4 o;
  o.x = t[kc + 0][dr]; o.y = t[kc + 1][dr];
  o.z = t[kc + 2][dr]; o.w = t[kc + 3][dr];
  *(ushort4 *)(encT + ((size_t)n * DM + d0 + dr) * TE + k0 + kc) = o;
}

// ---------------------------------------------------------------- bf16 MFMA GEMM
// C[m][n] = scale * sum_k A[m][k]*B[n][k]   (both operands K-contiguous)
// 128x128 tile, 4 waves (2x2), each wave 4x4 16x16x32 MFMA tiles, BK=32.
__global__ __launch_bounds__(256) void gemm_bf16_mfma(
    const ushort *__restrict__ Ag, const ushort *__restrict__ Bg,
    float *__restrict__ Cg, int K, int N, size_t sA, size_t sB, size_t sC,
    float scale) {
  const int nb = blockIdx.z;
  const int n0 = blockIdx.x * 128;
  const int m0 = blockIdx.y * 128;
  const int tid = threadIdx.x;
  const int wave = tid >> 6, lane = tid & 63;
  const int wm = (wave >> 1) * 64, wn = (wave & 1) * 64;
  const int fr = lane & 15, quad = lane >> 4;
  const ushort *A = Ag + nb * sA + (size_t)m0 * K;
  const ushort *B = Bg + nb * sB + (size_t)n0 * K;
  __shared__ ushort As[128 * 32];
  __shared__ ushort Bs[128 * 32];
  f32x4 acc[4][4];
#pragma unroll
  for (int i = 0; i < 4; ++i)
#pragma unroll
    for (int c = 0; c < 4; ++c) acc[i][c] = (f32x4){0.f, 0.f, 0.f, 0.f};

  const int srow = tid >> 1;        // 0..127
  const int scol = (tid & 1) * 16;  // 0 or 16 (ushort offset)
  for (int kb = 0; kb < K; kb += 32) {
    uint4 av0 = *(const uint4 *)(A + (size_t)srow * K + kb + scol);
    uint4 av1 = *(const uint4 *)(A + (size_t)srow * K + kb + scol + 8);
    uint4 bv0 = *(const uint4 *)(B + (size_t)srow * K + kb + scol);
    uint4 bv1 = *(const uint4 *)(B + (size_t)srow * K + kb + scol + 8);
    __syncthreads();
    *(uint4 *)(&As[srow * 32 + scol]) = av0;
    *(uint4 *)(&As[srow * 32 + scol + 8]) = av1;
    *(uint4 *)(&Bs[srow * 32 + scol]) = bv0;
    *(uint4 *)(&Bs[srow * 32 + scol + 8]) = bv1;
    __syncthreads();
    bf16x8 af[4], bfv[4];
#pragma unroll
    for (int i = 0; i < 4; ++i)
      af[i] = *(const bf16x8 *)(&As[(wm + i * 16 + fr) * 32 + quad * 8]);
#pragma unroll
    for (int c = 0; c < 4; ++c)
      bfv[c] = *(const bf16x8 *)(&Bs[(wn + c * 16 + fr) * 32 + quad * 8]);
#pragma unroll
    for (int i = 0; i < 4; ++i)
#pragma unroll
      for (int c = 0; c < 4; ++c)
        acc[i][c] = __builtin_amdgcn_mfma_f32_16x16x32_bf16(af[i], bfv[c],
                                                            acc[i][c], 0, 0, 0);
  }
  float *Cb = Cg + nb * sC;
#pragma unroll
  for (int i = 0; i < 4; ++i)
#pragma unroll
    for (int c = 0; c < 4; ++c)
#pragma unroll
      for (int r = 0; r < 4; ++r)
        Cb[(size_t)(m0 + wm + i * 16 + quad * 4 + r) * N + n0 + wn + c * 16 + fr] =
            acc[i][c][r] * scale;
}

// ---------------------------------------------------------------- softmax
__global__ __launch_bounds__(64) void softmax_rows(
    const float *__restrict__ scores, float *__restrict__ out1) {
  const int row = blockIdx.x;  // n*TD + j
  const int n = row >> 10;
  const int j = row & 1023;
  const int tid = threadIdx.x;
  const float *s = scores + (size_t)row * TE;
  float v[6];
#pragma unroll
  for (int i = 0; i < 6; ++i) v[i] = s[tid + 64 * i];
  float m = v[0];
#pragma unroll
  for (int i = 1; i < 6; ++i) m = fmaxf(m, v[i]);
#pragma unroll
  for (int off = 32; off; off >>= 1) m = fmaxf(m, __shfl_xor(m, off));
  float e[6], sum = 0.f;
#pragma unroll
  for (int i = 0; i < 6; ++i) { e[i] = __expf(v[i] - m); sum += e[i]; }
#pragma unroll
  for (int off = 32; off; off >>= 1) sum += __shfl_xor(sum, off);
  const float r = 1.0f / sum;
  float *dst = out1 + (size_t)n * (2 * TD * TE) + (size_t)j * TE;
#pragma unroll
  for (int i = 0; i < 6; ++i) dst[tid + 64 * i] = e[i] * r;
}

// ---------------------------------------------------------------- cond_prob (parallel)
__global__ __launch_bounds__(256) void cond_prob2(
    const float *__restrict__ scores, const float *__restrict__ Tbuf,
    float *__restrict__ cpT) {
  const int n = blockIdx.z;
  const int j0 = blockIdx.y * 64;
  const int k0 = blockIdx.x * 64;
  const int tid = threadIdx.x;
  __shared__ float eL[82][65];

  {
    const int c4 = (tid & 15) * 4;
    const int r0 = tid >> 4;  // 0..15
    float4 tv = *(const float4 *)(Tbuf + n * TE + k0 + c4);
    const float it0 = 1.0f / tv.x, it1 = 1.0f / tv.y, it2 = 1.0f / tv.z,
                it3 = 1.0f / tv.w;
#pragma unroll
    for (int p = 0; p < 6; ++p) {
      const int r = r0 + p * 16;
      if (r < 82) {
        const int j = j0 + r;
        float4 s;
        if (j < TD) {
          s = *(const float4 *)(scores + ((size_t)n * TD + j) * TE + k0 + c4);
          s.x = __expf(s.x * it0); s.y = __expf(s.y * it1);
          s.z = __expf(s.z * it2); s.w = __expf(s.w * it3);
        } else {
          s = make_float4(0.f, 0.f, 0.f, 0.f);
        }
        eL[r][c4 + 0] = s.x; eL[r][c4 + 1] = s.y;
        eL[r][c4 + 2] = s.z; eL[r][c4 + 3] = s.w;
      }
    }
  }
  __syncthreads();

  const int k = tid & 63;
  const int jl0 = (tid >> 6) * 16;
  float e_r[35];
#pragma unroll
  for (int t = 0; t < 35; ++t) e_r[t] = eL[jl0 + t][k];
  float win = 0.f;
#pragma unroll
  for (int t = 15; t <= 33; ++t) win += e_r[t];
  float cp[16];
#pragma unroll
  for (int jl = 15; jl >= 0; --jl) {
    cp[jl] = e_r[jl] / (win + 1e-8f);
    if (jl > 0) win += e_r[jl - 1] - e_r[jl + 18];
  }
  float *dst = cpT + ((size_t)n * TE + k0 + k) * TD + j0 + jl0;
#pragma unroll
  for (int q = 0; q < 4; ++q)
    *(float4 *)(dst + q * 4) =
        make_float4(cp[q * 4], cp[q * 4 + 1], cp[q * 4 + 2], cp[q * 4 + 3]);
}

// ---------------------------------------------------------------- phase 1 (a scan)
__global__ __launch_bounds__(128) void phase1_a(
    const float *__restrict__ cpT, float *__restrict__ aT) {
  const int n = blockIdx.x;
  const int tid = threadIdx.x;
  const int j0 = tid * 8;
  __shared__ float qbuf[2][24 + TD];
  if (tid < 24) { qbuf[0][tid] = 0.f; qbuf[1][tid] = 0.f; }
  float a[8];
#pragma unroll
  for (int i = 0; i < 8; ++i) a[i] = 0.f;
  if (tid == 0) a[0] = 1.f;
  const float *cpn = cpT + (size_t)n * TE * TD;
  float *an = aT + (size_t)n * TE * TD;
  float4 c0 = *(const float4 *)(cpn + j0);
  float4 c1 = *(const float4 *)(cpn + j0 + 4);
  __syncthreads();
  for (int k = 0; k < TE; ++k) {
    const float cp[8] = {c0.x, c0.y, c0.z, c0.w, c1.x, c1.y, c1.z, c1.w};
    if (k + 1 < TE) {
      c0 = *(const float4 *)(cpn + (size_t)k * TD + j0);
      c1 = *(const float4 *)(cpn + (size_t)k * TD + j0 + 4);
    }
    float *q = &qbuf[k & 1][24];
    float4 q0 = make_float4(a[0] * cp[0], a[1] * cp[1], a[2] * cp[2], a[3] * cp[3]);
    float4 q1 = make_float4(a[4] * cp[4], a[5] * cp[5], a[6] * cp[6], a[7] * cp[7]);
    *(float4 *)(q + j0) = q0;
    *(float4 *)(q + j0 + 4) = q1;
    __syncthreads();
    float w[32];
#pragma unroll
    for (int b = 0; b < 8; ++b) {
      float4 t = *(const float4 *)(q + j0 - 24 + b * 4);
      w[b * 4 + 0] = t.x; w[b * 4 + 1] = t.y; w[b * 4 + 2] = t.z; w[b * 4 + 3] = t.w;
    }
    float s = 0.f;
#pragma unroll
    for (int t = 4; t <= 22; ++t) s += w[t];
    a[0] = s;
#pragma unroll
    for (int i = 1; i < 8; ++i) { s += w[22 + i] - w[3 + i]; a[i] = s; }
    *(float4 *)(an + (size_t)k * TD + j0) = make_float4(a[0], a[1], a[2], a[3]);
    *(float4 *)(an + (size_t)k * TD + j0 + 4) = make_float4(a[4], a[5], a[6], a[7]);
  }
}

// ---------------------------------------------------------------- phase 2 (B)
__global__ __launch_bounds__(256) void phase2_B(
    const float *__restrict__ cpT, const float *__restrict__ aT,
    float *__restrict__ BT) {
  const int k = blockIdx.x;
  const int n = blockIdx.y;
  const int tid = threadIdx.x;
  const float *cpc = cpT + ((size_t)n * TE + k) * TD;
  const float *ac = aT + ((size_t)n * TE + k) * TD;
  __shared__ float a_l[20 + TD];
  __shared__ float cp_l[TD + 24];
  float4 av = *(const float4 *)(ac + tid * 4);
  *(float4 *)(&a_l[20 + tid * 4]) = av;
  float4 cv = *(const float4 *)(cpc + tid * 4);
  if (tid == 255) cv.w = 0.f;  // cp[1023] never contributes (clamp rule)
  *(float4 *)(&cp_l[tid * 4]) = cv;
  if (tid < 20) a_l[tid] = 0.f;
  if (tid < 24) cp_l[TD + tid] = 0.f;
  __syncthreads();
  const int j0 = tid * 4;
  float ar[21], cpr[21];
#pragma unroll
  for (int t = 0; t < 21; ++t) ar[t] = a_l[20 + j0 - 19 + t];
#pragma unroll
  for (int t = 0; t < 21; ++t) cpr[t] = cp_l[j0 + t];
  float Bo[4];
#pragma unroll
  for (int i = 0; i < 4; ++i) {
    float W = 0.f, acc2 = 0.f;
#pragma unroll
    for (int d = 19; d >= 2; --d) {
      W += cpr[i + 19 - d];
      acc2 = fmaf(ar[19 + i - d], W, acc2);
    }
    Bo[i] = acc2;
  }
  *(float4 *)(BT + ((size_t)n * TE + k) * TD + j0) =
      make_float4(Bo[0], Bo[1], Bo[2], Bo[3]);
}

// ---------------------------------------------------------------- transpose (+ bf16 copy)
__global__ __launch_bounds__(256) void transpose_B(
    const float *__restrict__ BT, float *__restrict__ out1,
    ushort *__restrict__ Bh) {
  __shared__ float tile[32][33];
  const int n = blockIdx.z;
  const int k0 = blockIdx.x * 32;
  const int j0 = blockIdx.y * 32;
  const int tx = threadIdx.x & 31;
  const int ty = threadIdx.x >> 5;  // 0..7
  const float *src = BT + (size_t)n * TE * TD;
#pragma unroll
  for (int r = 0; r < 4; ++r) {
    const int kk = ty + r * 8;
    tile[kk][tx] = src[(size_t)(k0 + kk) * TD + j0 + tx];
  }
  __syncthreads();
  float *dst = out1 + (size_t)n * (2 * TD * TE) + (size_t)TD * TE;
#pragma unroll
  for (int r = 0; r < 4; ++r) {
    const int jj = ty + r * 8;
    const float val = tile[tx][jj];
    dst[(size_t)(j0 + jj) * TE + k0 + tx] = val;
    Bh[((size_t)n * TD + j0 + jj) * TE + k0 + tx] = f2bf(val);
  }
}

// ---------------------------------------------------------------- launch
extern "C" void kernel_launch(void *const *d_in, const int *in_sizes, int n_in,
                              void *d_out, int out_size, void *d_ws,
                              size_t ws_size, hipStream_t stream) {
  (void)in_sizes; (void)n_in; (void)out_size; (void)ws_size;
  const float *enc = (const float *)d_in[0];  // [32][384][512]
  const float *mel = (const float *)d_in[1];  // [32][1024][512]
  float *out = (float *)d_out;
  float *out0 = out;                         // att_out [32][1024][512]
  float *out1 = out + (size_t)NB * TD * DM;  // stacked [32][2][1024][384]

  const size_t SZ = (size_t)NB * TD * TE;    // 12,582,912 floats
  float *ws = (float *)d_ws;
  float *ws_scores = ws;       // scores [n][j][k]; later BT
  float *ws_cpT = ws + SZ;     // cond_prob [n][k][j] (holds ench+melh before)
  float *ws_aT = ws + 2 * SZ;  // a [n][k][j] (holds Bh after phase2)
  float *ws_T = ws + 3 * SZ;   // T [n][k]
  ushort *encTb = (ushort *)(ws + 3 * SZ + NB * TE);  // encT bf16 [n][d][k]
  ushort *ench = (ushort *)ws_cpT;                    // bf16 [n][k][d]
  ushort *melh = (ushort *)ws_cpT + (size_t)NB * TE * DM;  // bf16 [n][j][d]
  ushort *Bh = (ushort *)ws_aT;                       // bf16 [n][j][k]
  float *ws_BT = ws_scores;

  conv_bf16<<<(NB * TD * DM) / (256 * 8), 256, 0, stream>>>(mel, melh);
  conv_encT<<<dim3(DM / 32, TE / 32, NB), 256, 0, stream>>>(enc, ench, encTb);
  gen_T<<<48, 256, 0, stream>>>(ws_T);
  gemm_bf16_mfma<<<dim3(TE / 128, TD / 128, NB), 256, 0, stream>>>(
      melh, ench, ws_scores, DM, TE, (size_t)TD * DM, (size_t)TE * DM,
      (size_t)TD * TE, 0.0441941738241592f);
  softmax_rows<<<NB * TD, 64, 0, stream>>>(ws_scores, out1);
  cond_prob2<<<dim3(TE / 64, TD / 64, NB), 256, 0, stream>>>(ws_scores, ws_T, ws_cpT);
  phase1_a<<<NB, 128, 0, stream>>>(ws_cpT, ws_aT);
  phase2_B<<<dim3(TE, NB), 256, 0, stream>>>(ws_cpT, ws_aT, ws_BT);
  transpose_B<<<dim3(TE / 32, TD / 32, NB), 256, 0, stream>>>(ws_BT, out1, Bh);
  gemm_bf16_mfma<<<dim3(DM / 128, TD / 128, NB), 256, 0, stream>>>(
      Bh, encTb, out0, TE, DM, (size_t)TD * TE, (size_t)DM * TE,
      (size_t)TD * DM, 1.0f);
}